// Round 5
// baseline (1911.759 us; speedup 1.0000x reference)
//
#include <hip/hip_runtime.h>
#include <stdint.h>

// ---- types ----
using f32x4  = __attribute__((ext_vector_type(4))) float;
using bf16x8 = __attribute__((ext_vector_type(8))) __bf16;

static __device__ __forceinline__ unsigned int f2bf_u(float f) {
  union { float f; unsigned int u; } v; v.f = f;
  return (v.u + 0x7fffu + ((v.u >> 16) & 1u)) >> 16;
}
static __device__ __forceinline__ unsigned short f2bf(float f) {
  return (unsigned short)f2bf_u(f);
}

static __device__ __forceinline__ void gload_lds16(const void* g, void* l) {
  __builtin_amdgcn_global_load_lds((const __attribute__((address_space(1))) void*)g,
                                   (__attribute__((address_space(3))) void*)l,
                                   16, 0, 0);
}

static __device__ __forceinline__ int swz(int row) { return (row & 3) ^ ((row >> 2) & 3); }

// DPP butterfly add over 8-lane groups (lanes replicated every 8).
// Pairing order identical to ((a0+a1)+(a2+a3))+((a4+a5)+(a6+a7)).
template <int CTRL>
static __device__ __forceinline__ float dppadd(float x) {
  int xi = __builtin_bit_cast(int, x);
  int yi = __builtin_amdgcn_update_dpp(0, xi, CTRL, 0xF, 0xF, true);
  return x + __builtin_bit_cast(float, yi);
}
static __device__ __forceinline__ float redsum8(float x) {
  float t = dppadd<0xB1>(x);   // quad_perm [1,0,3,2] : xor 1
  t = dppadd<0x4E>(t);         // quad_perm [2,3,0,1] : xor 2
  t = dppadd<0x124>(t);        // row_ror:4 == xor 4 under 8-lane replication
  return t;
}

// ---- fp32 -> bf16 convert (X) ----
__global__ __launch_bounds__(256) void k_cvt_bf16(const float* __restrict__ in,
                                                  unsigned short* __restrict__ out) {
  int i = blockIdx.x * 256 + threadIdx.x;
  float4 v = ((const float4*)in)[i];
  ushort4 o;
  o.x = f2bf(v.x); o.y = f2bf(v.y); o.z = f2bf(v.z); o.w = f2bf(v.w);
  ((ushort4*)out)[i] = o;
}

// ---- transpose + convert weights: in (E,R,C) f32 -> out (E,C,R) bf16 ----
__global__ __launch_bounds__(256) void k_transpose_cvt(const float* __restrict__ in,
                                                       unsigned short* __restrict__ out,
                                                       int R, int C) {
  __shared__ float tile[32][33];
  int e = blockIdx.z;
  const float* ip = in + (size_t)e * R * C;
  unsigned short* op = out + (size_t)e * R * C;
  int c0 = blockIdx.x * 32, r0 = blockIdx.y * 32;
  int tx = threadIdx.x, ty = threadIdx.y;   // block (32,8)
  #pragma unroll
  for (int i = ty; i < 32; i += 8)
    tile[i][tx] = ip[(size_t)(r0 + i) * C + c0 + tx];
  __syncthreads();
  #pragma unroll
  for (int i = ty; i < 32; i += 8)
    op[(size_t)(c0 + i) * R + r0 + tx] = f2bf(tile[tx][i]);
}

// ---- gating GEMM1: Hg = relu(x @ gW1 + gb1), fp32 vector (precision-critical:
// feeds the chaotic scan's > comparisons; k-order identical to prior passing round) ----
// 256x128 tile, BK=16, 16x8 per thread (LDS bytes/FMA 0.75 vs 1.0 at 8x8).
__global__ __launch_bounds__(256, 2) void k_gemm_f32_relu(const float* __restrict__ A,
                                                          const float* __restrict__ Bm,
                                                          const float* __restrict__ bias,
                                                          float* __restrict__ C) {
  const int K = 1024, N = 4096;
  __shared__ float As[16][256];
  __shared__ float Bs[16][128];
  int n0 = blockIdx.x * 128, m0 = blockIdx.y * 256;
  int t = threadIdx.x;
  int tm = t >> 4, tn = t & 15;
  float acc[16][8];
  #pragma unroll
  for (int i = 0; i < 16; ++i)
    #pragma unroll
    for (int j = 0; j < 8; ++j) acc[i][j] = 0.f;

  for (int k0 = 0; k0 < K; k0 += 16) {
    __syncthreads();
    #pragma unroll
    for (int cc = 0; cc < 4; ++cc) {      // A tile 256x16, transposed into As[k][m]
      int c = t + cc * 256;
      int m = c >> 2, kq = c & 3;
      float4 v = *(const float4*)&A[(size_t)(m0 + m) * K + k0 + kq * 4];
      As[kq * 4 + 0][m] = v.x; As[kq * 4 + 1][m] = v.y;
      As[kq * 4 + 2][m] = v.z; As[kq * 4 + 3][m] = v.w;
    }
    #pragma unroll
    for (int cc = 0; cc < 2; ++cc) {      // B tile 16x128
      int c = t + cc * 256;
      int kr = c >> 5, nq = c & 31;
      *(float4*)&Bs[kr][nq * 4] = *(const float4*)&Bm[(size_t)(k0 + kr) * N + n0 + nq * 4];
    }
    __syncthreads();
    #pragma unroll
    for (int kk = 0; kk < 16; ++kk) {
      float a[16], b[8];
      #pragma unroll
      for (int q = 0; q < 4; ++q)
        *(float4*)&a[q * 4] = *(const float4*)&As[kk][tm * 16 + q * 4];
      *(float4*)&b[0] = *(const float4*)&Bs[kk][tn * 8];
      *(float4*)&b[4] = *(const float4*)&Bs[kk][tn * 8 + 4];
      #pragma unroll
      for (int i = 0; i < 16; ++i)
        #pragma unroll
        for (int j = 0; j < 8; ++j) acc[i][j] = fmaf(a[i], b[j], acc[i][j]);
    }
  }
  float bb[8];
  #pragma unroll
  for (int j = 0; j < 8; ++j) bb[j] = bias[n0 + tn * 8 + j];
  #pragma unroll
  for (int i = 0; i < 16; ++i) {
    int m = m0 + tm * 16 + i;
    float* crow = C + (size_t)m * N + n0 + tn * 8;
    float4 v0, v1;
    v0.x = fmaxf(acc[i][0] + bb[0], 0.f); v0.y = fmaxf(acc[i][1] + bb[1], 0.f);
    v0.z = fmaxf(acc[i][2] + bb[2], 0.f); v0.w = fmaxf(acc[i][3] + bb[3], 0.f);
    v1.x = fmaxf(acc[i][4] + bb[4], 0.f); v1.y = fmaxf(acc[i][5] + bb[5], 0.f);
    v1.z = fmaxf(acc[i][6] + bb[6], 0.f); v1.w = fmaxf(acc[i][7] + bb[7], 0.f);
    *(float4*)crow = v0; *(float4*)(crow + 4) = v1;
  }
}

// ---- gating GEMM2 + softmax ----
__global__ __launch_bounds__(256) void k_gate2_softmax(const float* __restrict__ Hg,
                                                       const float* __restrict__ gW2,
                                                       const float* __restrict__ gb2,
                                                       float* __restrict__ probs) {
  __shared__ float red[4][8];
  int b = blockIdx.x, t = threadIdx.x;
  const float* hrow = Hg + (size_t)b * 4096;
  float acc[8];
  #pragma unroll
  for (int e = 0; e < 8; ++e) acc[e] = 0.f;
  #pragma unroll
  for (int i = 0; i < 4; ++i) {
    int kk = t + i * 256;
    float4 h = ((const float4*)hrow)[kk];
    const float* wr = gW2 + (size_t)kk * 32;
    #pragma unroll
    for (int j = 0; j < 4; ++j) {
      float hv = (&h.x)[j];
      #pragma unroll
      for (int e = 0; e < 8; ++e) acc[e] = fmaf(hv, wr[j * 8 + e], acc[e]);
    }
  }
  #pragma unroll
  for (int e = 0; e < 8; ++e) {
    float v = acc[e];
    for (int off = 32; off > 0; off >>= 1) v += __shfl_down(v, off);
    acc[e] = v;
  }
  int lane = t & 63, w = t >> 6;
  if (lane == 0) {
    #pragma unroll
    for (int e = 0; e < 8; ++e) red[w][e] = acc[e];
  }
  __syncthreads();
  if (t == 0) {
    float l[8], mx = -1e30f;
    #pragma unroll
    for (int e = 0; e < 8; ++e) {
      l[e] = red[0][e] + red[1][e] + red[2][e] + red[3][e] + gb2[e];
      mx = fmaxf(mx, l[e]);
    }
    float sum = 0.f;
    #pragma unroll
    for (int e = 0; e < 8; ++e) { l[e] = expf(l[e] - mx); sum += l[e]; }
    float inv = 1.f / sum;
    #pragma unroll
    for (int e = 0; e < 8; ++e) probs[b * 8 + e] = l[e] * inv;
  }
}

// ---- fused: block 0 = lane-parallel gating scan; blocks 1.. = expert GEMM1 ----
// egemm1: Hs_e[m][n] = bf16( relu(Xb@W1T_e^T + b1) )   (gate applied in k_reduce)
// LDS union kept at 16.5 KB (scan chunks of 256 rows) so GEMM occupancy is VGPR-bound.
__global__ __launch_bounds__(256) void k_egemm1_scan(const unsigned short* __restrict__ Xb,
                                                     const unsigned short* __restrict__ W1T,
                                                     const float* __restrict__ eb1,
                                                     const float* __restrict__ probs,
                                                     float* __restrict__ gateOut,
                                                     unsigned short* __restrict__ Hs) {
  __shared__ __align__(16) char smem[16512];
  int bid = blockIdx.x;
  int t = threadIdx.x;

  if (bid == 0) {
    // ---- gating scan, dispatched first so it overlaps the GEMM blocks ----
    float* P  = (float*)smem;        // [256][8]
    float* G  = P + 2048;            // [256][8]
    int*  flg = (int*)(G + 2048);
    int e = t & 7;
    float rta = 0.f, maxn = 0.f;
    for (int ch = 0; ch < 16; ++ch) {
      __syncthreads();
      #pragma unroll
      for (int i = 0; i < 2; ++i)
        ((float4*)P)[t + i * 256] = ((const float4*)(probs + ch * 2048))[t + i * 256];
      __syncthreads();
      if (t < 64) {
        float s_cur = P[e];
        for (int r = 0; r < 256; ++r) {
          float s_nxt = P[(((r + 1) & 255) << 3) + e];
          float a = rta + s_cur;
          float sum = redsum8(a);
          float thr = fmaf(sum, 0.125f, 0.1f);
          bool msk = a > thr;
          unsigned long long bal = __ballot(msk);
          float d = msk ? 0.f : s_cur;
          float norm = redsum8(d);
          float inv = (norm == 0.f) ? 1.f : (1.f / norm);
          float g = d * inv;
          float base = (bal != 0ull) ? (a - s_cur) : a;
          rta = base + g;
          maxn = fmaxf(maxn, norm);
          if (t < 8) G[(r << 3) + e] = g;
          s_cur = s_nxt;
        }
      }
      __syncthreads();
      #pragma unroll
      for (int i = 0; i < 2; ++i)
        ((float4*)(gateOut + ch * 2048))[t + i * 256] = ((const float4*)G)[t + i * 256];
    }
    if (t == 0) *flg = (maxn > 0.f) ? 1 : 0;
    __syncthreads();
    if (*flg == 0) {       // jnp.all(g==0) fallback -> uniform 1/8
      for (int i = t; i < 32768; i += 256) gateOut[i] = 0.125f;
    }
    return;
  }

  // ---- expert GEMM1 ----
  char* Asm = smem;            // 128 rows x 32 k bf16, chunk-swizzled
  char* Bsm = smem + 8192;
  int b = bid - 1;
  int e = b >> 10;
  int rest = b & 1023;
  int m0 = (rest >> 5) << 7, n0 = (rest & 31) << 7;
  int lane = t & 63, w = t >> 6;
  int wm = w >> 1, wn = w & 1;
  const unsigned short* Ab = Xb;
  const unsigned short* Bb = W1T + ((size_t)e << 22);
  f32x4 acc[4][4];
  #pragma unroll
  for (int mi = 0; mi < 4; ++mi)
    #pragma unroll
    for (int ni = 0; ni < 4; ++ni) acc[mi][ni] = (f32x4){0.f, 0.f, 0.f, 0.f};

  for (int kt = 0; kt < 1024; kt += 32) {
    __syncthreads();
    {
      int p = (w << 6) + lane;
      int row = p >> 2, h = (p & 3) ^ swz(row);
      int p2 = p + 256;
      int row2 = p2 >> 2, h2 = (p2 & 3) ^ swz(row2);
      char* la = Asm + (w << 10);
      char* lb = Bsm + (w << 10);
      gload_lds16(Ab + (size_t)(m0 + row) * 1024 + kt + h * 8, la);
      gload_lds16(Ab + (size_t)(m0 + row2) * 1024 + kt + h2 * 8, la + 4096);
      gload_lds16(Bb + (size_t)(n0 + row) * 1024 + kt + h * 8, lb);
      gload_lds16(Bb + (size_t)(n0 + row2) * 1024 + kt + h2 * 8, lb + 4096);
    }
    __syncthreads();
    bf16x8 af[4], bfr[4];
    #pragma unroll
    for (int mi = 0; mi < 4; ++mi) {
      int ra = (wm << 6) + (mi << 4) + (lane & 15);
      int hh = (lane >> 4) ^ swz(ra);
      af[mi] = *(const bf16x8*)(Asm + ra * 64 + hh * 16);
    }
    #pragma unroll
    for (int ni = 0; ni < 4; ++ni) {
      int rb = (wn << 6) + (ni << 4) + (lane & 15);
      int hh = (lane >> 4) ^ swz(rb);
      bfr[ni] = *(const bf16x8*)(Bsm + rb * 64 + hh * 16);
    }
    // operand-swapped: D[n][m] -> lane's 4 regs = 4 consecutive n at fixed m
    #pragma unroll
    for (int mi = 0; mi < 4; ++mi)
      #pragma unroll
      for (int ni = 0; ni < 4; ++ni)
        acc[mi][ni] = __builtin_amdgcn_mfma_f32_16x16x32_bf16(bfr[ni], af[mi], acc[mi][ni], 0, 0, 0);
  }
  // epilogue (swapped layout): m = m0+(wm<<6)+(mi<<4)+col; n = n0+(wn<<6)+(ni<<4)+(quad<<2)+r
  const float* b1e = eb1 + (e << 12);
  unsigned short* Ho = Hs + ((size_t)e << 24);
  int col = lane & 15, quad = lane >> 4;
  float4 bq[4];
  #pragma unroll
  for (int ni = 0; ni < 4; ++ni)
    bq[ni] = *(const float4*)&b1e[n0 + (wn << 6) + (ni << 4) + (quad << 2)];
  #pragma unroll
  for (int mi = 0; mi < 4; ++mi) {
    int m = m0 + (wm << 6) + (mi << 4) + col;
    unsigned short* orow = Ho + (size_t)m * 4096 + n0 + (wn << 6) + (quad << 2);
    #pragma unroll
    for (int ni = 0; ni < 4; ++ni) {
      float v0 = fmaxf(acc[mi][ni][0] + bq[ni].x, 0.f);
      float v1 = fmaxf(acc[mi][ni][1] + bq[ni].y, 0.f);
      float v2 = fmaxf(acc[mi][ni][2] + bq[ni].z, 0.f);
      float v3 = fmaxf(acc[mi][ni][3] + bq[ni].w, 0.f);
      uint2 u;
      u.x = f2bf_u(v0) | (f2bf_u(v1) << 16);
      u.y = f2bf_u(v2) | (f2bf_u(v3) << 16);
      *(uint2*)(orow + (ni << 4)) = u;
    }
  }
}

// ---- expert GEMM2, per-expert partials: part_e = Hs_e @ W2T_e^T (fp32, ungated) ----
// grid 2048 flat: bid = n*256 + m*8 + e. 128x128 tile, K=4096. Operand-swapped epilogue.
__global__ __launch_bounds__(256) void k_egemm2(const unsigned short* __restrict__ Hs,
                                                const unsigned short* __restrict__ W2T,
                                                float* __restrict__ partLo,
                                                float* __restrict__ partHi) {
  __shared__ __align__(16) char Asm[8192];   // 128 x 32
  __shared__ __align__(16) char Bsm[8192];   // 128 x 32
  int bid = blockIdx.x;
  int n0 = (bid >> 8) << 7;
  int rem = bid & 255;
  int m0 = (rem >> 3) << 7;
  int e = rem & 7;
  int t = threadIdx.x, lane = t & 63, w = t >> 6;
  int wm = w >> 1, wn = w & 1;
  const unsigned short* Ab = Hs + ((size_t)e << 24);
  const unsigned short* Bb = W2T + ((size_t)e << 22);
  f32x4 acc[4][4];
  #pragma unroll
  for (int mi = 0; mi < 4; ++mi)
    #pragma unroll
    for (int ni = 0; ni < 4; ++ni) acc[mi][ni] = (f32x4){0.f, 0.f, 0.f, 0.f};

  for (int kt = 0; kt < 4096; kt += 32) {
    __syncthreads();
    {
      int p = (w << 6) + lane;
      int row = p >> 2, h = (p & 3) ^ swz(row);
      int p2 = p + 256;
      int row2 = p2 >> 2, h2 = (p2 & 3) ^ swz(row2);
      char* la = Asm + (w << 10);
      char* lb = Bsm + (w << 10);
      gload_lds16(Ab + (size_t)(m0 + row) * 4096 + kt + h * 8, la);
      gload_lds16(Ab + (size_t)(m0 + row2) * 4096 + kt + h2 * 8, la + 4096);
      gload_lds16(Bb + (size_t)(n0 + row) * 4096 + kt + h * 8, lb);
      gload_lds16(Bb + (size_t)(n0 + row2) * 4096 + kt + h2 * 8, lb + 4096);
    }
    __syncthreads();
    bf16x8 af[4], bfr[4];
    #pragma unroll
    for (int mi = 0; mi < 4; ++mi) {
      int ra = (wm << 6) + (mi << 4) + (lane & 15);
      int hh = (lane >> 4) ^ swz(ra);
      af[mi] = *(const bf16x8*)(Asm + ra * 64 + hh * 16);
    }
    #pragma unroll
    for (int ni = 0; ni < 4; ++ni) {
      int rb = (wn << 6) + (ni << 4) + (lane & 15);
      int hh = (lane >> 4) ^ swz(rb);
      bfr[ni] = *(const bf16x8*)(Bsm + rb * 64 + hh * 16);
    }
    #pragma unroll
    for (int mi = 0; mi < 4; ++mi)
      #pragma unroll
      for (int ni = 0; ni < 4; ++ni)
        acc[mi][ni] = __builtin_amdgcn_mfma_f32_16x16x32_bf16(bfr[ni], af[mi], acc[mi][ni], 0, 0, 0);
  }
  float* Pe = (e < 4 ? partLo + ((size_t)e << 22) : partHi + ((size_t)(e - 4) << 22));
  int col = lane & 15, quad = lane >> 4;
  #pragma unroll
  for (int mi = 0; mi < 4; ++mi) {
    int m = m0 + (wm << 6) + (mi << 4) + col;
    float* orow = Pe + (size_t)m * 1024 + n0 + (wn << 6) + (quad << 2);
    #pragma unroll
    for (int ni = 0; ni < 4; ++ni) {
      float4 v;
      v.x = acc[mi][ni][0]; v.y = acc[mi][ni][1];
      v.z = acc[mi][ni][2]; v.w = acc[mi][ni][3];
      *(float4*)(orow + (ni << 4)) = v;
    }
  }
}

// ---- reduce: Out[m][n] = sum_e g[m][e] * (part_e[m][n] + b2[e][n]) ----
__global__ __launch_bounds__(256) void k_reduce(const float* __restrict__ partLo,
                                                const float* __restrict__ partHi,
                                                const float* __restrict__ eb2,
                                                const float* __restrict__ gate,
                                                float* __restrict__ Out) {
  int idx = blockIdx.x * 256 + threadIdx.x;   // float4 index
  int m = idx >> 8, n4 = idx & 255;
  float4 g0 = *(const float4*)(gate + (m << 3));
  float4 g1 = *(const float4*)(gate + (m << 3) + 4);
  float ga[8] = {g0.x, g0.y, g0.z, g0.w, g1.x, g1.y, g1.z, g1.w};
  float4 acc = make_float4(0.f, 0.f, 0.f, 0.f);
  #pragma unroll
  for (int e = 0; e < 8; ++e) {
    const float* Pe = (e < 4 ? partLo + ((size_t)e << 22) : partHi + ((size_t)(e - 4) << 22));
    float4 pv = ((const float4*)Pe)[idx];
    float4 bv = ((const float4*)(eb2 + (e << 10)))[n4];
    acc.x += ga[e] * (pv.x + bv.x);
    acc.y += ga[e] * (pv.y + bv.y);
    acc.z += ga[e] * (pv.z + bv.z);
    acc.w += ga[e] * (pv.w + bv.w);
  }
  ((float4*)Out)[idx] = acc;
}

extern "C" void kernel_launch(void* const* d_in, const int* in_sizes, int n_in,
                              void* d_out, int out_size, void* d_ws, size_t ws_size,
                              hipStream_t stream) {
  (void)in_sizes; (void)n_in; (void)out_size; (void)ws_size;
  const float* x   = (const float*)d_in[0];
  const float* gW1 = (const float*)d_in[1];
  const float* gb1 = (const float*)d_in[2];
  const float* gW2 = (const float*)d_in[3];
  const float* gb2 = (const float*)d_in[4];
  const float* eW1 = (const float*)d_in[5];
  const float* eb1 = (const float*)d_in[6];
  const float* eW2 = (const float*)d_in[7];
  const float* eb2 = (const float*)d_in[8];
  float* out = (float*)d_out;
  float* gateOut = out + (size_t)4096 * 1024;   // second output g (4096x8x1)

  char* ws = (char*)d_ws;
  unsigned short* Xb  = (unsigned short*)ws;                   //   8 MB [0,8)
  unsigned short* W1T = (unsigned short*)(ws + (8ull  << 20)); //  64 MB [8,72)   (8,4096,1024)
  unsigned short* W2T = (unsigned short*)(ws + (72ull << 20)); //  64 MB [72,136) (8,1024,4096)
  float*          prb = (float*)        (ws + (136ull << 20)); // 128 KB
  float*          Hg  = (float*)        (ws + (137ull << 20)); //  64 MB [137,201)
  unsigned short* Hs  = (unsigned short*)(ws + (201ull << 20)); // 256 MB [201,457) (8,4096,4096)
  // partials overlay regions dead by egemm2 time: W1T (e=0..3), Hg (e=4..7)
  float* partLo = (float*)(ws + (8ull   << 20));   // 64 MB: part[0..3]
  float* partHi = (float*)(ws + (137ull << 20));   // 64 MB: part[4..7]

  k_cvt_bf16<<<4096, 256, 0, stream>>>(x, Xb);
  k_transpose_cvt<<<dim3(128, 32, 8), dim3(32, 8), 0, stream>>>(eW1, W1T, 1024, 4096);
  k_transpose_cvt<<<dim3(32, 128, 8), dim3(32, 8), 0, stream>>>(eW2, W2T, 4096, 1024);
  k_gemm_f32_relu<<<dim3(32, 16), 256, 0, stream>>>(x, gW1, gb1, Hg);
  k_gate2_softmax<<<4096, 256, 0, stream>>>(Hg, gW2, gb2, prb);
  k_egemm1_scan<<<8193, 256, 0, stream>>>(Xb, W1T, eb1, prb, gateOut, Hs);
  k_egemm2<<<2048, 256, 0, stream>>>(Hs, W2T, partLo, partHi);
  k_reduce<<<4096, 256, 0, stream>>>(partLo, partHi, eb2, gateOut, out);
}

// Round 6
// 1656.270 us; speedup vs baseline: 1.1543x; 1.1543x over previous
//
#include <hip/hip_runtime.h>
#include <stdint.h>

// ---- types ----
using f32x4  = __attribute__((ext_vector_type(4))) float;
using bf16x8 = __attribute__((ext_vector_type(8))) __bf16;

static __device__ __forceinline__ unsigned int f2bf_u(float f) {
  union { float f; unsigned int u; } v; v.f = f;
  return (v.u + 0x7fffu + ((v.u >> 16) & 1u)) >> 16;
}
static __device__ __forceinline__ unsigned short f2bf(float f) {
  return (unsigned short)f2bf_u(f);
}

static __device__ __forceinline__ void gload_lds16(const void* g, void* l) {
  __builtin_amdgcn_global_load_lds((const __attribute__((address_space(1))) void*)g,
                                   (__attribute__((address_space(3))) void*)l,
                                   16, 0, 0);
}

static __device__ __forceinline__ int swz(int row) { return (row & 3) ^ ((row >> 2) & 3); }

// DPP butterfly add over 8-lane groups (lanes replicated every 8).
// Pairing order identical to ((a0+a1)+(a2+a3))+((a4+a5)+(a6+a7)).
template <int CTRL>
static __device__ __forceinline__ float dppadd(float x) {
  int xi = __builtin_bit_cast(int, x);
  int yi = __builtin_amdgcn_update_dpp(0, xi, CTRL, 0xF, 0xF, true);
  return x + __builtin_bit_cast(float, yi);
}
static __device__ __forceinline__ float redsum8(float x) {
  float t = dppadd<0xB1>(x);   // quad_perm [1,0,3,2] : xor 1
  t = dppadd<0x4E>(t);         // quad_perm [2,3,0,1] : xor 2
  t = dppadd<0x124>(t);        // row_ror:4 == xor 4 under 8-lane replication
  return t;
}

// stage a 256-row x 32-k bf16 tile pair into LDS (wave-uniform lds base + lane*16)
static __device__ __forceinline__ void stage_tiles(const unsigned short* __restrict__ gA,
                                                   const unsigned short* __restrict__ gB,
                                                   int strideK, int kt, int w, int lane,
                                                   char* bufA, char* bufB) {
  #pragma unroll
  for (int r = 0; r < 2; ++r) {
    int c = r * 512 + w * 64 + lane;
    int row = c >> 2, h = (c & 3) ^ swz(row);
    size_t go = (size_t)row * strideK + kt + h * 8;
    int lo = (r * 512 + w * 64) << 4;
    gload_lds16(gA + go, bufA + lo);
    gload_lds16(gB + go, bufB + lo);
  }
}

// ---- fp32 -> bf16 convert (X) ----
__global__ __launch_bounds__(256) void k_cvt_bf16(const float* __restrict__ in,
                                                  unsigned short* __restrict__ out) {
  int i = blockIdx.x * 256 + threadIdx.x;
  float4 v = ((const float4*)in)[i];
  ushort4 o;
  o.x = f2bf(v.x); o.y = f2bf(v.y); o.z = f2bf(v.z); o.w = f2bf(v.w);
  ((ushort4*)out)[i] = o;
}

// ---- transpose + convert weights: in (E,R,C) f32 -> out (E,C,R) bf16 ----
__global__ __launch_bounds__(256) void k_transpose_cvt(const float* __restrict__ in,
                                                       unsigned short* __restrict__ out,
                                                       int R, int C) {
  __shared__ float tile[32][33];
  int e = blockIdx.z;
  const float* ip = in + (size_t)e * R * C;
  unsigned short* op = out + (size_t)e * R * C;
  int c0 = blockIdx.x * 32, r0 = blockIdx.y * 32;
  int tx = threadIdx.x, ty = threadIdx.y;   // block (32,8)
  #pragma unroll
  for (int i = ty; i < 32; i += 8)
    tile[i][tx] = ip[(size_t)(r0 + i) * C + c0 + tx];
  __syncthreads();
  #pragma unroll
  for (int i = ty; i < 32; i += 8)
    op[(size_t)(c0 + i) * R + r0 + tx] = f2bf(tile[tx][i]);
}

// ---- gating GEMM1: Hg = relu(x @ gW1 + gb1), fp32 vector (precision-critical:
// feeds the chaotic scan's > comparisons; k-order identical to prior passing rounds) ----
__global__ __launch_bounds__(256, 2) void k_gemm_f32_relu(const float* __restrict__ A,
                                                          const float* __restrict__ Bm,
                                                          const float* __restrict__ bias,
                                                          float* __restrict__ C) {
  const int K = 1024, N = 4096;
  __shared__ float As[16][256];
  __shared__ float Bs[16][128];
  int n0 = blockIdx.x * 128, m0 = blockIdx.y * 256;
  int t = threadIdx.x;
  int tm = t >> 4, tn = t & 15;
  float acc[16][8];
  #pragma unroll
  for (int i = 0; i < 16; ++i)
    #pragma unroll
    for (int j = 0; j < 8; ++j) acc[i][j] = 0.f;

  for (int k0 = 0; k0 < K; k0 += 16) {
    __syncthreads();
    #pragma unroll
    for (int cc = 0; cc < 4; ++cc) {      // A tile 256x16, transposed into As[k][m]
      int c = t + cc * 256;
      int m = c >> 2, kq = c & 3;
      float4 v = *(const float4*)&A[(size_t)(m0 + m) * K + k0 + kq * 4];
      As[kq * 4 + 0][m] = v.x; As[kq * 4 + 1][m] = v.y;
      As[kq * 4 + 2][m] = v.z; As[kq * 4 + 3][m] = v.w;
    }
    #pragma unroll
    for (int cc = 0; cc < 2; ++cc) {      // B tile 16x128
      int c = t + cc * 256;
      int kr = c >> 5, nq = c & 31;
      *(float4*)&Bs[kr][nq * 4] = *(const float4*)&Bm[(size_t)(k0 + kr) * N + n0 + nq * 4];
    }
    __syncthreads();
    #pragma unroll
    for (int kk = 0; kk < 16; ++kk) {
      float a[16], b[8];
      #pragma unroll
      for (int q = 0; q < 4; ++q)
        *(float4*)&a[q * 4] = *(const float4*)&As[kk][tm * 16 + q * 4];
      *(float4*)&b[0] = *(const float4*)&Bs[kk][tn * 8];
      *(float4*)&b[4] = *(const float4*)&Bs[kk][tn * 8 + 4];
      #pragma unroll
      for (int i = 0; i < 16; ++i)
        #pragma unroll
        for (int j = 0; j < 8; ++j) acc[i][j] = fmaf(a[i], b[j], acc[i][j]);
    }
  }
  float bb[8];
  #pragma unroll
  for (int j = 0; j < 8; ++j) bb[j] = bias[n0 + tn * 8 + j];
  #pragma unroll
  for (int i = 0; i < 16; ++i) {
    int m = m0 + tm * 16 + i;
    float* crow = C + (size_t)m * N + n0 + tn * 8;
    float4 v0, v1;
    v0.x = fmaxf(acc[i][0] + bb[0], 0.f); v0.y = fmaxf(acc[i][1] + bb[1], 0.f);
    v0.z = fmaxf(acc[i][2] + bb[2], 0.f); v0.w = fmaxf(acc[i][3] + bb[3], 0.f);
    v1.x = fmaxf(acc[i][4] + bb[4], 0.f); v1.y = fmaxf(acc[i][5] + bb[5], 0.f);
    v1.z = fmaxf(acc[i][6] + bb[6], 0.f); v1.w = fmaxf(acc[i][7] + bb[7], 0.f);
    *(float4*)crow = v0; *(float4*)(crow + 4) = v1;
  }
}

// ---- gating GEMM2 + softmax ----
__global__ __launch_bounds__(256) void k_gate2_softmax(const float* __restrict__ Hg,
                                                       const float* __restrict__ gW2,
                                                       const float* __restrict__ gb2,
                                                       float* __restrict__ probs) {
  __shared__ float red[4][8];
  int b = blockIdx.x, t = threadIdx.x;
  const float* hrow = Hg + (size_t)b * 4096;
  float acc[8];
  #pragma unroll
  for (int e = 0; e < 8; ++e) acc[e] = 0.f;
  #pragma unroll
  for (int i = 0; i < 4; ++i) {
    int kk = t + i * 256;
    float4 h = ((const float4*)hrow)[kk];
    const float* wr = gW2 + (size_t)kk * 32;
    #pragma unroll
    for (int j = 0; j < 4; ++j) {
      float hv = (&h.x)[j];
      #pragma unroll
      for (int e = 0; e < 8; ++e) acc[e] = fmaf(hv, wr[j * 8 + e], acc[e]);
    }
  }
  #pragma unroll
  for (int e = 0; e < 8; ++e) {
    float v = acc[e];
    for (int off = 32; off > 0; off >>= 1) v += __shfl_down(v, off);
    acc[e] = v;
  }
  int lane = t & 63, w = t >> 6;
  if (lane == 0) {
    #pragma unroll
    for (int e = 0; e < 8; ++e) red[w][e] = acc[e];
  }
  __syncthreads();
  if (t == 0) {
    float l[8], mx = -1e30f;
    #pragma unroll
    for (int e = 0; e < 8; ++e) {
      l[e] = red[0][e] + red[1][e] + red[2][e] + red[3][e] + gb2[e];
      mx = fmaxf(mx, l[e]);
    }
    float sum = 0.f;
    #pragma unroll
    for (int e = 0; e < 8; ++e) { l[e] = expf(l[e] - mx); sum += l[e]; }
    float inv = 1.f / sum;
    #pragma unroll
    for (int e = 0; e < 8; ++e) probs[b * 8 + e] = l[e] * inv;
  }
}

// ---- fused: block 0 = lane-parallel gating scan; blocks 1.. = expert GEMM1 ----
// egemm1: Hs_e[m][n] = bf16( relu(Xb@W1T_e^T + b1) ), 256x256 tile, 512 thr,
// double-buffered LDS (1 block/CU -> dbuf hides the barrier drain).
// bid map: g=e*16+n, bid-1 = (g>>3)*128 + m*8 + (g&7) -> same-(e,n) B-tile per XCD.
__global__ __launch_bounds__(512, 2) void k_egemm1_scan(const unsigned short* __restrict__ Xb,
                                                        const unsigned short* __restrict__ W1T,
                                                        const float* __restrict__ eb1,
                                                        const float* __restrict__ probs,
                                                        float* __restrict__ gateOut,
                                                        unsigned short* __restrict__ Hs) {
  __shared__ __align__(16) char smem[65536];
  int bid = blockIdx.x;
  int t = threadIdx.x;

  if (bid == 0) {
    // ---- gating scan, dispatched first so it overlaps the GEMM blocks ----
    float* P  = (float*)smem;        // [256][8]
    float* G  = P + 2048;            // [256][8]
    int*  flg = (int*)(G + 2048);
    int e = t & 7;
    float rta = 0.f, maxn = 0.f;
    for (int ch = 0; ch < 16; ++ch) {
      __syncthreads();
      ((float4*)P)[t] = ((const float4*)(probs + ch * 2048))[t];
      __syncthreads();
      if (t < 64) {
        float s_cur = P[e];
        for (int r = 0; r < 256; ++r) {
          float s_nxt = P[(((r + 1) & 255) << 3) + e];
          float a = rta + s_cur;
          float sum = redsum8(a);
          float thr = fmaf(sum, 0.125f, 0.1f);
          bool msk = a > thr;
          unsigned long long bal = __ballot(msk);
          float d = msk ? 0.f : s_cur;
          float norm = redsum8(d);
          float inv = (norm == 0.f) ? 1.f : (1.f / norm);
          float g = d * inv;
          float base = (bal != 0ull) ? (a - s_cur) : a;
          rta = base + g;
          maxn = fmaxf(maxn, norm);
          if (t < 8) G[(r << 3) + e] = g;
          s_cur = s_nxt;
        }
      }
      __syncthreads();
      ((float4*)(gateOut + ch * 2048))[t] = ((const float4*)G)[t];
    }
    if (t == 0) *flg = (maxn > 0.f) ? 1 : 0;
    __syncthreads();
    if (*flg == 0) {       // jnp.all(g==0) fallback -> uniform 1/8
      for (int i = t; i < 32768; i += 512) gateOut[i] = 0.125f;
    }
    return;
  }

  // ---- expert GEMM1, 256x256, K=1024 ----
  int b = bid - 1;
  int G8 = b >> 7, within = b & 127;
  int m = within >> 3, x = within & 7;
  int g = G8 * 8 + x;
  int e = g >> 4, n = g & 15;
  int m0 = m << 8, n0 = n << 8;
  int lane = t & 63, w = t >> 6;
  int wm = w >> 2, wn = w & 3;            // wave grid 2m x 4n, each 128x64
  const unsigned short* Ag = Xb + (size_t)m0 * 1024;
  const unsigned short* Bg = W1T + ((size_t)e << 22) + (size_t)n0 * 1024;
  f32x4 acc[8][4];
  #pragma unroll
  for (int mi = 0; mi < 8; ++mi)
    #pragma unroll
    for (int ni = 0; ni < 4; ++ni) acc[mi][ni] = (f32x4){0.f, 0.f, 0.f, 0.f};

  stage_tiles(Ag, Bg, 1024, 0, w, lane, smem, smem + 16384);
  __syncthreads();
  for (int kt = 0; kt < 1024; kt += 32) {
    int cur = (kt >> 5) & 1;
    char* cA = smem + (cur << 15);
    char* cB = cA + 16384;
    if (kt + 32 < 1024) {
      char* nA = smem + ((cur ^ 1) << 15);
      stage_tiles(Ag, Bg, 1024, kt + 32, w, lane, nA, nA + 16384);
    }
    bf16x8 af[8], bfr[4];
    #pragma unroll
    for (int mi = 0; mi < 8; ++mi) {
      int ra = (wm << 7) + (mi << 4) + (lane & 15);
      int hh = (lane >> 4) ^ swz(ra);
      af[mi] = *(const bf16x8*)(cA + ra * 64 + hh * 16);
    }
    #pragma unroll
    for (int ni = 0; ni < 4; ++ni) {
      int rb = (wn << 6) + (ni << 4) + (lane & 15);
      int hh = (lane >> 4) ^ swz(rb);
      bfr[ni] = *(const bf16x8*)(cB + rb * 64 + hh * 16);
    }
    // operand-swapped: lane's 4 acc regs = 4 consecutive n at fixed m
    #pragma unroll
    for (int mi = 0; mi < 8; ++mi)
      #pragma unroll
      for (int ni = 0; ni < 4; ++ni)
        acc[mi][ni] = __builtin_amdgcn_mfma_f32_16x16x32_bf16(bfr[ni], af[mi], acc[mi][ni], 0, 0, 0);
    __syncthreads();
  }
  // epilogue: m = m0+wm*128+mi*16+col; n = n0+wn*64+ni*16+quad*4+r
  const float* b1e = eb1 + (e << 12);
  unsigned short* Ho = Hs + ((size_t)e << 24);
  int col = lane & 15, quad = lane >> 4;
  float4 bq[4];
  #pragma unroll
  for (int ni = 0; ni < 4; ++ni)
    bq[ni] = *(const float4*)&b1e[n0 + (wn << 6) + (ni << 4) + (quad << 2)];
  #pragma unroll
  for (int mi = 0; mi < 8; ++mi) {
    int mm = m0 + (wm << 7) + (mi << 4) + col;
    unsigned short* orow = Ho + (size_t)mm * 4096 + n0 + (wn << 6) + (quad << 2);
    #pragma unroll
    for (int ni = 0; ni < 4; ++ni) {
      float v0 = fmaxf(acc[mi][ni][0] + bq[ni].x, 0.f);
      float v1 = fmaxf(acc[mi][ni][1] + bq[ni].y, 0.f);
      float v2 = fmaxf(acc[mi][ni][2] + bq[ni].z, 0.f);
      float v3 = fmaxf(acc[mi][ni][3] + bq[ni].w, 0.f);
      uint2 u;
      u.x = f2bf_u(v0) | (f2bf_u(v1) << 16);
      u.y = f2bf_u(v2) | (f2bf_u(v3) << 16);
      *(uint2*)(orow + (ni << 4)) = u;
    }
  }
}

// ---- expert GEMM2, per-expert partials: part_e = Hs_e @ W2T_e^T (fp32, ungated) ----
// 256x256 tile, 512 thr, K=4096, double-buffered LDS.
// bid map: g=e*16+m, bid = (g>>3)*32 + n*8 + (g&7) -> same-(e,m) Hs-tile per XCD.
__global__ __launch_bounds__(512, 2) void k_egemm2(const unsigned short* __restrict__ Hs,
                                                   const unsigned short* __restrict__ W2T,
                                                   float* __restrict__ partLo,
                                                   float* __restrict__ partHi) {
  __shared__ __align__(16) char smem[65536];
  int bid = blockIdx.x;
  int G8 = bid >> 5, within = bid & 31;
  int n = within >> 3, x = within & 7;
  int g = G8 * 8 + x;
  int e = g >> 4, m = g & 15;
  int m0 = m << 8, n0 = n << 8;
  int t = threadIdx.x, lane = t & 63, w = t >> 6;
  int wm = w >> 2, wn = w & 3;
  const unsigned short* Ag = Hs + ((size_t)e << 24) + (size_t)m0 * 4096;
  const unsigned short* Bg = W2T + ((size_t)e << 22) + (size_t)n0 * 4096;
  f32x4 acc[8][4];
  #pragma unroll
  for (int mi = 0; mi < 8; ++mi)
    #pragma unroll
    for (int ni = 0; ni < 4; ++ni) acc[mi][ni] = (f32x4){0.f, 0.f, 0.f, 0.f};

  stage_tiles(Ag, Bg, 4096, 0, w, lane, smem, smem + 16384);
  __syncthreads();
  for (int kt = 0; kt < 4096; kt += 32) {
    int cur = (kt >> 5) & 1;
    char* cA = smem + (cur << 15);
    char* cB = cA + 16384;
    if (kt + 32 < 4096) {
      char* nA = smem + ((cur ^ 1) << 15);
      stage_tiles(Ag, Bg, 4096, kt + 32, w, lane, nA, nA + 16384);
    }
    bf16x8 af[8], bfr[4];
    #pragma unroll
    for (int mi = 0; mi < 8; ++mi) {
      int ra = (wm << 7) + (mi << 4) + (lane & 15);
      int hh = (lane >> 4) ^ swz(ra);
      af[mi] = *(const bf16x8*)(cA + ra * 64 + hh * 16);
    }
    #pragma unroll
    for (int ni = 0; ni < 4; ++ni) {
      int rb = (wn << 6) + (ni << 4) + (lane & 15);
      int hh = (lane >> 4) ^ swz(rb);
      bfr[ni] = *(const bf16x8*)(cB + rb * 64 + hh * 16);
    }
    #pragma unroll
    for (int mi = 0; mi < 8; ++mi)
      #pragma unroll
      for (int ni = 0; ni < 4; ++ni)
        acc[mi][ni] = __builtin_amdgcn_mfma_f32_16x16x32_bf16(bfr[ni], af[mi], acc[mi][ni], 0, 0, 0);
    __syncthreads();
  }
  float* Pe = (e < 4 ? partLo + ((size_t)e << 22) : partHi + ((size_t)(e - 4) << 22));
  int col = lane & 15, quad = lane >> 4;
  #pragma unroll
  for (int mi = 0; mi < 8; ++mi) {
    int mm = m0 + (wm << 7) + (mi << 4) + col;
    float* orow = Pe + (size_t)mm * 1024 + n0 + (wn << 6) + (quad << 2);
    #pragma unroll
    for (int ni = 0; ni < 4; ++ni) {
      float4 v;
      v.x = acc[mi][ni][0]; v.y = acc[mi][ni][1];
      v.z = acc[mi][ni][2]; v.w = acc[mi][ni][3];
      *(float4*)(orow + (ni << 4)) = v;
    }
  }
}

// ---- reduce: Out[m][n] = sum_e g[m][e] * (part_e[m][n] + b2[e][n]) ----
__global__ __launch_bounds__(256) void k_reduce(const float* __restrict__ partLo,
                                                const float* __restrict__ partHi,
                                                const float* __restrict__ eb2,
                                                const float* __restrict__ gate,
                                                float* __restrict__ Out) {
  int idx = blockIdx.x * 256 + threadIdx.x;   // float4 index
  int m = idx >> 8, n4 = idx & 255;
  float4 g0 = *(const float4*)(gate + (m << 3));
  float4 g1 = *(const float4*)(gate + (m << 3) + 4);
  float ga[8] = {g0.x, g0.y, g0.z, g0.w, g1.x, g1.y, g1.z, g1.w};
  float4 acc = make_float4(0.f, 0.f, 0.f, 0.f);
  #pragma unroll
  for (int e = 0; e < 8; ++e) {
    const float* Pe = (e < 4 ? partLo + ((size_t)e << 22) : partHi + ((size_t)(e - 4) << 22));
    float4 pv = ((const float4*)Pe)[idx];
    float4 bv = ((const float4*)(eb2 + (e << 10)))[n4];
    acc.x += ga[e] * (pv.x + bv.x);
    acc.y += ga[e] * (pv.y + bv.y);
    acc.z += ga[e] * (pv.z + bv.z);
    acc.w += ga[e] * (pv.w + bv.w);
  }
  ((float4*)Out)[idx] = acc;
}

extern "C" void kernel_launch(void* const* d_in, const int* in_sizes, int n_in,
                              void* d_out, int out_size, void* d_ws, size_t ws_size,
                              hipStream_t stream) {
  (void)in_sizes; (void)n_in; (void)out_size; (void)ws_size;
  const float* x   = (const float*)d_in[0];
  const float* gW1 = (const float*)d_in[1];
  const float* gb1 = (const float*)d_in[2];
  const float* gW2 = (const float*)d_in[3];
  const float* gb2 = (const float*)d_in[4];
  const float* eW1 = (const float*)d_in[5];
  const float* eb1 = (const float*)d_in[6];
  const float* eW2 = (const float*)d_in[7];
  const float* eb2 = (const float*)d_in[8];
  float* out = (float*)d_out;
  float* gateOut = out + (size_t)4096 * 1024;   // second output g (4096x8x1)

  char* ws = (char*)d_ws;
  unsigned short* Xb  = (unsigned short*)ws;                   //   8 MB [0,8)
  unsigned short* W1T = (unsigned short*)(ws + (8ull  << 20)); //  64 MB [8,72)   (8,4096,1024)
  unsigned short* W2T = (unsigned short*)(ws + (72ull << 20)); //  64 MB [72,136) (8,1024,4096)
  float*          prb = (float*)        (ws + (136ull << 20)); // 128 KB
  float*          Hg  = (float*)        (ws + (137ull << 20)); //  64 MB [137,201)
  unsigned short* Hs  = (unsigned short*)(ws + (201ull << 20)); // 256 MB [201,457) (8,4096,4096)
  // partials overlay regions dead by egemm2 time: W1T (e=0..3), Hg (e=4..7)
  float* partLo = (float*)(ws + (8ull   << 20));   // 64 MB: part[0..3]
  float* partHi = (float*)(ws + (137ull << 20));   // 64 MB: part[4..7]

  k_cvt_bf16<<<4096, 256, 0, stream>>>(x, Xb);
  k_transpose_cvt<<<dim3(128, 32, 8), dim3(32, 8), 0, stream>>>(eW1, W1T, 1024, 4096);
  k_transpose_cvt<<<dim3(32, 128, 8), dim3(32, 8), 0, stream>>>(eW2, W2T, 4096, 1024);
  k_gemm_f32_relu<<<dim3(32, 16), 256, 0, stream>>>(x, gW1, gb1, Hg);
  k_gate2_softmax<<<4096, 256, 0, stream>>>(Hg, gW2, gb2, prb);
  k_egemm1_scan<<<2049, 512, 0, stream>>>(Xb, W1T, eb1, prb, gateOut, Hs);
  k_egemm2<<<512, 512, 0, stream>>>(Hs, W2T, partLo, partHi);
  k_reduce<<<4096, 256, 0, stream>>>(partLo, partHi, eb2, gateOut, out);
}